// Round 5
// baseline (327.411 us; speedup 1.0000x reference)
//
#include <hip/hip_runtime.h>

// DayAdapter: out[b,t,e] = softsign( x[b,t,:] @ W[day[b]] + bias[day[b]] )
// x: [64,1024,512] f32, day_ids: [64] i32, W: [24,512,512] f32, bias: [24,512] f32
//
// Round 7: never-drain pipeline (proper T3/T4), sized for 3 blocks/CU.
// Theory: 2-barrier skeleton's vmcnt(0) drain each K-step gives ~50% duty
// cycle on the HBM request stream -> 3.2 TB/s = ~51% of 6.3 ceiling, invariant
// across R0-R6 tweaks. Fix the drain itself:
//   BK=32, NT=16 steps. As[2] dbuf (20.5KB), Bs[3] TRIPLE buf (24.6KB) ->
//   45KB LDS -> 3 blocks/CU. B gll16 issued TWO steps ahead; A f32->reg
//   issued one step ahead, cvt+ds_write late (T14). ONE raw s_barrier per
//   step preceded by s_waitcnt vmcnt(2) lgkmcnt(0): two gll16 stay in flight
//   across every barrier; vmcnt never 0 in the loop. Buffer rotation removes
//   the WAR hazard that needed barrier #1 (writes target a buffer nobody
//   reads this step; its readers finished before the previous barrier).
// Bank patterns (all 2-way = free, m136): B chunk swizzle c = cp^(n&3)^((n>>2)&3)
// within 64B rows; As LDA=40 (80B row, 20 words: rows 8-apart alias = 2-way).
// Epilogue: R2's direct stores (R6's LDS-transpose epilogue regressed).

#define DIM 512
#define SEQ 1024
#define NB 64
#define NDAYS 24
#define BM 128
#define BN 128
#define BK 32
#define NT 16
#define LDA 40          // A row stride in bf16: 80 B

typedef __bf16 bf16x8 __attribute__((ext_vector_type(8)));
typedef __bf16 bf16x4 __attribute__((ext_vector_type(4)));
typedef float  f32x4  __attribute__((ext_vector_type(4)));

__device__ __forceinline__ void gll16(const void* g, void* l) {
    __builtin_amdgcn_global_load_lds(
        (const __attribute__((address_space(1))) unsigned int*)g,
        (__attribute__((address_space(3))) unsigned int*)l,
        16, 0, 0);
}

// ---- kernel 1: Wt[d][n][k] = bf16(W[d][k][n]) ----
__global__ __launch_bounds__(256)
void transpose_w_kernel(const float* __restrict__ W, __bf16* __restrict__ Wt) {
    __shared__ __bf16 T[32][33];
    const int d  = blockIdx.z;
    const int k0 = blockIdx.x * 32;
    const int n0 = blockIdx.y * 32;
    const int tx = threadIdx.x & 31;
    const int ty = threadIdx.x >> 5;   // 0..7
    const float* Wd = W + (size_t)d * DIM * DIM;
    #pragma unroll
    for (int i = 0; i < 4; ++i) {
        const int k = ty + i * 8;
        T[tx][k] = (__bf16)Wd[(size_t)(k0 + k) * DIM + n0 + tx];  // coalesced f32 read
    }
    __syncthreads();
    __bf16* Wtd = Wt + (size_t)d * DIM * DIM;
    #pragma unroll
    for (int i = 0; i < 4; ++i) {
        const int n = ty + i * 8;
        Wtd[(size_t)(n0 + n) * DIM + k0 + tx] = T[n][tx];         // coalesced bf16 write
    }
}

// ---- kernel 2: main GEMM + bias + softsign ----
__global__ __launch_bounds__(256, 3)
void day_adapter_kernel(const float* __restrict__ x,
                        const int*   __restrict__ day_ids,
                        const __bf16* __restrict__ Wt,
                        const float* __restrict__ bias,
                        float*       __restrict__ out)
{
    __shared__ __align__(16) __bf16 As[2][BM][LDA];   // 2 x 10240 B
    __shared__ __align__(16) __bf16 Bs[3][BN * BK];   // 3 x 8192 B

    // XCD swizzle: L = xcdslot(3b) | ntile(2b) | hi(6b); the 4 ntiles of one
    // (m,b) share L mod 8 -> same XCD under round-robin dispatch.
    const int L  = blockIdx.x;
    const int g  = (L >> 3) & 3;
    const int mb = (L & 7) | ((L >> 5) << 3);   // 0..511
    const int m  = mb & 7;
    const int bb = mb >> 3;

    const int n0  = g * BN;
    const int m0  = m * BM;
    const int tid = threadIdx.x;
    const int day = day_ids[bb];

    const float*  xb  = x   + (size_t)bb  * SEQ * DIM + (size_t)m0 * DIM;
    const __bf16* Wtb = Wt  + (size_t)day * DIM * DIM + (size_t)n0 * DIM;
    float*        ob  = out + (size_t)bb  * SEQ * DIM + (size_t)m0 * DIM + n0;

    const int wave = tid >> 6;
    const int lane = tid & 63;
    const int wm   = (wave >> 1) * 64;
    const int wn   = (wave & 1) * 64;
    const int l15  = lane & 15;
    const int quad = lane >> 4;          // 0..3
    const int kq   = quad * 8;           // k-offset of this lane's frag chunk

    // A staging map: 4 float4/thread; row = p*32 + (tid>>3), col = (tid&7)*4
    // -> per instr: 8 rows x 128 B dense segments.
    const int arow = tid >> 3;
    const int acol = (tid & 7) * 4;
    // B staging map: 2 gll16/thread; slot s = p*256+tid; n = p*64 + (tid>>2),
    // cp = tid&3, stored chunk c = cp ^ (n&3) ^ ((n>>2)&3) (XOR involution).
    const int bn_ = tid >> 2;
    const int bcp = tid & 3;

    char* BsB = (char*)Bs;

    f32x4 acc[4][4];
    const f32x4 zero = {0.f, 0.f, 0.f, 0.f};
    #pragma unroll
    for (int i = 0; i < 4; ++i)
        #pragma unroll
        for (int j = 0; j < 4; ++j) acc[i][j] = zero;

    float4 fA[4];   // in-flight A tile, statically indexed -> VGPRs

    auto issueA = [&](int t) {
        #pragma unroll
        for (int p = 0; p < 4; ++p)
            fA[p] = *(const float4*)(xb + (size_t)(p * 32 + arow) * DIM
                                     + t * BK + acol);
    };
    auto issueB = [&](int t) {
        char* dst = BsB + (size_t)(t % 3) * (BN * BK * 2);
        #pragma unroll
        for (int p = 0; p < 2; ++p) {
            const int n = p * 64 + bn_;
            const int c = bcp ^ (n & 3) ^ ((n >> 2) & 3);
            gll16(Wtb + (size_t)n * DIM + t * BK + c * 8,
                  dst + (size_t)(p * 256 + (tid & ~63)) * 16);
        }
    };
    auto writeA = [&](int buf) {
        #pragma unroll
        for (int p = 0; p < 4; ++p) {
            const float4 f = fA[p];
            bf16x4 v;
            v[0] = (__bf16)f.x; v[1] = (__bf16)f.y;
            v[2] = (__bf16)f.z; v[3] = (__bf16)f.w;
            *(bf16x4*)&As[buf][p * 32 + arow][acol] = v;
        }
    };

    // ---- prologue: A(0), B(0), B(1) in flight ----
    issueA(0);                                    // queue: A4
    issueB(0);                                    // queue: A4 B2
    issueB(1);                                    // queue: A4 B2 B2
    writeA(0);                                    // compiler waits fA (vmcnt(4))
    asm volatile("s_waitcnt vmcnt(2) lgkmcnt(0)" ::: "memory");  // B(0) landed
    __builtin_amdgcn_sched_barrier(0);
    __builtin_amdgcn_s_barrier();
    __builtin_amdgcn_sched_barrier(0);

    #pragma unroll
    for (int t = 0; t < NT; ++t) {
        const int Ac = t & 1;
        const int Bc = t % 3;                     // constant-folded (full unroll)

        if (t < NT - 1) issueA(t + 1);            // in flight across this step
        if (t < NT - 2) issueB(t + 2);            // two steps ahead

        bf16x8 af[4], bfr[4];
        #pragma unroll
        for (int i = 0; i < 4; ++i)
            af[i] = *(const bf16x8*)&As[Ac][wm + i * 16 + l15][kq];
        #pragma unroll
        for (int j = 0; j < 4; ++j) {
            const int n  = wn + j * 16 + l15;
            const int cp = quad ^ (n & 3) ^ ((n >> 2) & 3);
            bfr[j] = *(const bf16x8*)((const char*)&Bs[Bc][0]
                                      + (size_t)n * 64 + cp * 16);
        }
        #pragma unroll
        for (int i = 0; i < 4; ++i)
            #pragma unroll
            for (int j = 0; j < 4; ++j)
                acc[i][j] = __builtin_amdgcn_mfma_f32_16x16x32_bf16(
                    af[i], bfr[j], acc[i][j], 0, 0, 0);

        if (t < NT - 1) {
            writeA(Ac ^ 1);                       // no reader of As[Ac^1] this step
            // B(t+1) landed (only B(t+2)'s 2 gll16 may remain); A writes visible.
            asm volatile("s_waitcnt vmcnt(2) lgkmcnt(0)" ::: "memory");
            __builtin_amdgcn_sched_barrier(0);
            __builtin_amdgcn_s_barrier();
            __builtin_amdgcn_sched_barrier(0);
        }
    }

    // -- epilogue: bias + softsign (R2-style direct stores) --
    float bv[4];
    #pragma unroll
    for (int j = 0; j < 4; ++j)
        bv[j] = bias[(size_t)day * DIM + n0 + wn + j * 16 + l15];

    #pragma unroll
    for (int i = 0; i < 4; ++i) {
        const int rbase = wm + i * 16 + quad * 4;        // C/D: row = quad*4 + reg
        #pragma unroll
        for (int j = 0; j < 4; ++j) {
            const int col = wn + j * 16 + l15;           // C/D: col = lane&15
            #pragma unroll
            for (int r = 0; r < 4; ++r) {
                const float y = acc[i][j][r] + bv[j];
                ob[(size_t)(rbase + r) * DIM + col] = y / (1.0f + fabsf(y));
            }
        }
    }
}

extern "C" void kernel_launch(void* const* d_in, const int* in_sizes, int n_in,
                              void* d_out, int out_size, void* d_ws, size_t ws_size,
                              hipStream_t stream) {
    const float* x       = (const float*)d_in[0];
    const int*   day_ids = (const int*)  d_in[1];
    const float* W       = (const float*)d_in[2];
    const float* bias    = (const float*)d_in[3];
    float*       out     = (float*)d_out;
    __bf16*      Wt      = (__bf16*)d_ws;   // 24*512*512*2 = 12.58 MB

    dim3 tgrid(DIM / 32, DIM / 32, NDAYS);  // (16,16,24)
    transpose_w_kernel<<<tgrid, 256, 0, stream>>>(W, Wt);

    day_adapter_kernel<<<dim3(2048), 256, 0, stream>>>(x, day_ids, Wt, bias, out);
}